// Round 9
// baseline (543.562 us; speedup 1.0000x reference)
//
#include <hip/hip_runtime.h>

// out[n,k] = sum_{i,j} x[n,i] * W[k,i,j] * x[n,j]   (N=262144 rows, D=32)
// GEMM form: z[n, p=i*32+j] = x[n,i]*x[n,j];  out = z (N x 1024) @ Wf (1024 x 32),
// Wf[p][k] = W[k*1024 + p].  v_mfma_f32_32x32x16_f16, fp32 accumulate.
//
// R9 = DIAGNOSTIC round. Six structures (R4-R8) all plateau at 31.5-34.5us
// (~529 TF) while every pipe model says ~11-13us. Since R4 the kernel runs
// faster than the harness's 268MB poison fills (~40us), so it fell out of
// the top-5 rocprof view: NO counters since R2. This kernel = R8 structure
// + runtime `iters` (=2) repeating the full deterministic pipeline, pushing
// each dispatch to ~60-65us so the top-5 rows become OUR kernel with full
// counters (MfmaUtil / VALUBusy / Occupancy / FETCH / WRITE / VGPR).
// dur_us this round is sacrificial (~2x). Output identical (same stores
// re-written; runtime loop bound defeats CSE/DCE of the second pass).

typedef _Float16 f16x2 __attribute__((ext_vector_type(2)));
typedef _Float16 f16x8 __attribute__((ext_vector_type(8)));
typedef float    f32x16 __attribute__((ext_vector_type(16)));

static __device__ __forceinline__ unsigned int pk2_f16(float lo, float hi) {
    return __builtin_bit_cast(unsigned int, __builtin_amdgcn_cvt_pkrtz(lo, hi));
}

struct XPack {
    unsigned int xpk[2][16];   // packed f16 pair (x[2c], x[2c+1]) per row-tile
    unsigned int xsel[2][8];   // hi-selected pair regs feeding A-slots
};

static __device__ __forceinline__
void load_xg(float4 xg[16], const float* __restrict__ x, long wrow0, int rl) {
    #pragma unroll
    for (int r = 0; r < 2; ++r) {
        const float4* xr = (const float4*)(x + (wrow0 + r * 32 + rl) * 32);
        #pragma unroll
        for (int c = 0; c < 8; ++c) xg[r * 8 + c] = xr[c];
    }
}

static __device__ __forceinline__
void pack_rows(const float4 xg[16], int hi, XPack& P) {
    #pragma unroll
    for (int r = 0; r < 2; ++r) {
        #pragma unroll
        for (int c = 0; c < 8; ++c) {
            float4 v = xg[r * 8 + c];
            P.xpk[r][2 * c + 0] = pk2_f16(v.x, v.y);
            P.xpk[r][2 * c + 1] = pk2_f16(v.z, v.w);
        }
        // xsel[r][q*4+t]: pair for A-slots (b=2t,2t+1), parity q:
        //   j = q*16 + hi*8 + 2t -> pair index c = q*8 + hi*4 + t
        #pragma unroll
        for (int q = 0; q < 2; ++q)
            #pragma unroll
            for (int t = 0; t < 4; ++t)
                P.xsel[r][q * 4 + t] = hi ? P.xpk[r][q * 8 + 4 + t]
                                          : P.xpk[r][q * 8 + t];
    }
}

static __device__ __forceinline__
void kloop_store(const unsigned short* __restrict__ btab, const XPack& P,
                 int lane, int hi, int rl, long wrow0, float* __restrict__ out) {
    f32x16 acc[2];
    #pragma unroll
    for (int r = 0; r < 2; ++r)
        #pragma unroll
        for (int e = 0; e < 16; ++e) acc[r][e] = 0.0f;

    // 64 K-steps of K=16 (p = 16s+k), fully unrolled (R5/R8 structure)
    #pragma unroll
    for (int s = 0; s < 64; ++s) {
        f16x8 bfrag = *(const f16x8*)(&btab[(s * 64 + lane) * 8]);
        const int ii = s >> 1;           // i (fixed within step)
        const int q  = s & 1;
        const unsigned int sel = (ii & 1) ? 0x03020302u : 0x01000100u;
        #pragma unroll
        for (int r = 0; r < 2; ++r) {
            unsigned int w = P.xpk[r][ii >> 1];
            f16x2 xi2 = __builtin_bit_cast(f16x2, __builtin_amdgcn_perm(w, w, sel));
            union { f16x8 v; unsigned int uu[4]; } a;
            #pragma unroll
            for (int t = 0; t < 4; ++t) {
                f16x2 p = xi2 * __builtin_bit_cast(f16x2, P.xsel[r][q * 4 + t]);
                a.uu[t] = __builtin_bit_cast(unsigned int, p);
            }
            acc[r] = __builtin_amdgcn_mfma_f32_32x32x16_f16(a.v, bfrag, acc[r], 0, 0, 0);
        }
    }

    // store: col = lane&31 (k), row = (e&3) + 8*(e>>2) + 4*hi
    #pragma unroll
    for (int r = 0; r < 2; ++r) {
        long n0 = wrow0 + r * 32;
        #pragma unroll
        for (int e = 0; e < 16; ++e) {
            int row = (e & 3) + 8 * (e >> 2) + 4 * hi;
            out[(n0 + row) * 32 + rl] = acc[r][e];
        }
    }
}

__global__ __launch_bounds__(512, 2)
void quadform_kernel(const float* __restrict__ x,
                     const float* __restrict__ W,
                     float* __restrict__ out,
                     int iters) {
    // btab[(s*64 + lane)*8 + b] = f16 of Wf[16s + (lane>>5)*8 + b][lane&31]
    __shared__ __align__(16) unsigned short btab[64 * 64 * 8];   // 64 KiB

    const int tid  = threadIdx.x;
    const int lane = tid & 63;
    const int wave = tid >> 6;
    const int hi   = lane >> 5;
    const int rl   = lane & 31;
    const long wrow0 = (long)blockIdx.x * 1024 + wave * 64;   // chunk0 wave base

    // ---- build LDS B-table from global W (fp32 -> f16 fragments), once ----
    #pragma unroll
    for (int f = 0; f < 8; ++f) {
        int idx = tid + f * 512;                 // 0..4095 fragments (s,l)
        int s = idx >> 6;
        int l = idx & 63;
        const float* src = W + (l & 31) * 1024 + s * 16 + ((l >> 5) << 3);
        float4 w0 = *(const float4*)(src);
        float4 w1 = *(const float4*)(src + 4);
        union { unsigned int ui[4]; uint4 u4; } pk;
        pk.ui[0] = pk2_f16(w0.x, w0.y);
        pk.ui[1] = pk2_f16(w0.z, w0.w);
        pk.ui[2] = pk2_f16(w1.x, w1.y);
        pk.ui[3] = pk2_f16(w1.z, w1.w);
        *(uint4*)(&btab[idx * 8]) = pk.u4;
    }
    __syncthreads();

    // ---- diagnostic loop: runtime bound (=2) repeats the full pipeline;
    //      identical stores each pass -> output unchanged, ~2x duration ----
    for (int it = 0; it < iters; ++it) {
        float4 xg[16];
        XPack P;
        load_xg(xg, x, wrow0, rl);                  // chunk 0
        pack_rows(xg, hi, P);
        load_xg(xg, x, wrow0 + 512, rl);            // prefetch chunk 1
        kloop_store(btab, P, lane, hi, rl, wrow0, out);
        pack_rows(xg, hi, P);                       // chunk 1
        kloop_store(btab, P, lane, hi, rl, wrow0 + 512, out);
    }
}

extern "C" void kernel_launch(void* const* d_in, const int* in_sizes, int n_in,
                              void* d_out, int out_size, void* d_ws, size_t ws_size,
                              hipStream_t stream) {
    const float* x = (const float*)d_in[0];
    const float* W = (const float*)d_in[1];
    float* out = (float*)d_out;
    int nrows = in_sizes[0] / 32;          // 262144
    int grid  = nrows / 1024;              // 256 blocks x 512 thr, 2 chunks each
    quadform_kernel<<<grid, 512, 0, stream>>>(x, W, out, 2);
}

// Round 10
// 34.159 us; speedup vs baseline: 15.9129x; 15.9129x over previous
//
#include <hip/hip_runtime.h>

// out[n,k] = sum_{i,j} x[n,i] * W[k,i,j] * x[n,j]   (N=262144 rows, D=32)
// GEMM form: z[n, p=i*32+j] = x[n,i]*x[n,j];  out = z (N x 1024) @ Wf (1024 x 32),
// Wf[p][k] = W[k*1024 + p].  v_mfma_f32_32x32x16_f16, fp32 accumulate.
//
// R10 vs R4-R9: SSA-PURE rewrite. R9's diagnostic (iters=2) showed ~1.3 GB
// of scratch traffic (FETCH 695MB/WRITE 756MB vs ~100 ideal) with MfmaUtil
// cycles exactly = 2x the 6.9us MFMA floor: the compiler keeps memory-typed
// locals (the f16x8/uint[4] UNION in the K-loop, the XPack struct-by-ref,
// float4 arrays passed to functions) on the stack. R2 showed the moderate
// form (29MB excess write, VGPR=88 under a 256 cap) in straight-line code.
// This kernel has ZERO memory-typed locals on the hot path: A-fragments are
// built as SSA values (v_perm + v_pk_mul_f16 + shufflevector), accumulators
// are named f32x16, all arrays literal-indexed under full unroll, no helper
// functions. Memory structure = R4 (btab in LDS, direct x loads, 512thr).

typedef _Float16 f16x2 __attribute__((ext_vector_type(2)));
typedef _Float16 f16x4 __attribute__((ext_vector_type(4)));
typedef _Float16 f16x8 __attribute__((ext_vector_type(8)));
typedef float    f32x16 __attribute__((ext_vector_type(16)));

static __device__ __forceinline__ unsigned int pk2_f16(float lo, float hi) {
    return __builtin_bit_cast(unsigned int, __builtin_amdgcn_cvt_pkrtz(lo, hi));
}
static __device__ __forceinline__ f16x2 u2h(unsigned int u) {
    return __builtin_bit_cast(f16x2, u);
}

__global__ __launch_bounds__(512, 2)
void quadform_kernel(const float* __restrict__ x,
                     const float* __restrict__ W,
                     float* __restrict__ out) {
    // btab[(s*64 + lane)*8 + b] = f16 of Wf[16s + (lane>>5)*8 + b][lane&31]
    __shared__ __align__(16) unsigned short btab[64 * 64 * 8];   // 64 KiB

    const int tid  = threadIdx.x;
    const int lane = tid & 63;
    const int wave = tid >> 6;
    const int hi   = lane >> 5;
    const int rl   = lane & 31;
    const long rowbase = (long)blockIdx.x * 512 + wave * 64;

    // ---- build LDS B-table from global W (fp32 -> f16 fragments) ----
    #pragma unroll
    for (int f = 0; f < 8; ++f) {
        int idx = tid + f * 512;                 // 0..4095 fragments (s,l)
        int s = idx >> 6;
        int l = idx & 63;
        const float* src = W + (l & 31) * 1024 + s * 16 + ((l >> 5) << 3);
        float4 w0 = *(const float4*)(src);
        float4 w1 = *(const float4*)(src + 4);
        uint4 pk;
        pk.x = pk2_f16(w0.x, w0.y);
        pk.y = pk2_f16(w0.z, w0.w);
        pk.z = pk2_f16(w1.x, w1.y);
        pk.w = pk2_f16(w1.z, w1.w);
        *(uint4*)(&btab[idx * 8]) = pk;
    }

    // ---- load + pack this lane's 2 rows (literal-indexed, fully unrolled) ----
    unsigned int xpk0[16], xpk1[16];     // packed f16 pair (x[2c], x[2c+1])
    {
        const float4* xr0 = (const float4*)(x + (rowbase + rl) * 32);
        const float4* xr1 = (const float4*)(x + (rowbase + 32 + rl) * 32);
        #pragma unroll
        for (int c = 0; c < 8; ++c) {
            float4 v0 = xr0[c];
            float4 v1 = xr1[c];
            xpk0[2 * c + 0] = pk2_f16(v0.x, v0.y);
            xpk0[2 * c + 1] = pk2_f16(v0.z, v0.w);
            xpk1[2 * c + 0] = pk2_f16(v1.x, v1.y);
            xpk1[2 * c + 1] = pk2_f16(v1.z, v1.w);
        }
    }

    // xsel[q*4+t]: pair-reg feeding A-slots (b=2t,2t+1) for step parity q:
    //   j = q*16 + hi*8 + 2t  ->  pair index c = q*8 + hi*4 + t
    unsigned int xsel0[8], xsel1[8];
    #pragma unroll
    for (int q = 0; q < 2; ++q)
        #pragma unroll
        for (int t = 0; t < 4; ++t) {
            xsel0[q * 4 + t] = hi ? xpk0[q * 8 + 4 + t] : xpk0[q * 8 + t];
            xsel1[q * 4 + t] = hi ? xpk1[q * 8 + 4 + t] : xpk1[q * 8 + t];
        }

    f32x16 accA, accB;
    #pragma unroll
    for (int e = 0; e < 16; ++e) { accA[e] = 0.0f; accB[e] = 0.0f; }

    __syncthreads();

    // ---- main K loop: 64 steps of K=16 (p = 16s+k), fully unrolled,
    //      A-fragment built purely in SSA (no unions / stack objects) ----
    #pragma unroll
    for (int s = 0; s < 64; ++s) {
        f16x8 bfrag = *(const f16x8*)(&btab[(s * 64 + lane) * 8]);
        const int ii = s >> 1;           // i (fixed within step)
        const int q  = s & 1;
        const unsigned int sel = (ii & 1) ? 0x03020302u : 0x01000100u;

        {   // tile 0
            unsigned int w = xpk0[ii >> 1];
            f16x2 xi2 = u2h(__builtin_amdgcn_perm(w, w, sel));
            f16x2 p0 = xi2 * u2h(xsel0[q * 4 + 0]);
            f16x2 p1 = xi2 * u2h(xsel0[q * 4 + 1]);
            f16x2 p2 = xi2 * u2h(xsel0[q * 4 + 2]);
            f16x2 p3 = xi2 * u2h(xsel0[q * 4 + 3]);
            f16x4 lo = __builtin_shufflevector(p0, p1, 0, 1, 2, 3);
            f16x4 hf = __builtin_shufflevector(p2, p3, 0, 1, 2, 3);
            f16x8 a  = __builtin_shufflevector(lo, hf, 0, 1, 2, 3, 4, 5, 6, 7);
            accA = __builtin_amdgcn_mfma_f32_32x32x16_f16(a, bfrag, accA, 0, 0, 0);
        }
        {   // tile 1
            unsigned int w = xpk1[ii >> 1];
            f16x2 xi2 = u2h(__builtin_amdgcn_perm(w, w, sel));
            f16x2 p0 = xi2 * u2h(xsel1[q * 4 + 0]);
            f16x2 p1 = xi2 * u2h(xsel1[q * 4 + 1]);
            f16x2 p2 = xi2 * u2h(xsel1[q * 4 + 2]);
            f16x2 p3 = xi2 * u2h(xsel1[q * 4 + 3]);
            f16x4 lo = __builtin_shufflevector(p0, p1, 0, 1, 2, 3);
            f16x4 hf = __builtin_shufflevector(p2, p3, 0, 1, 2, 3);
            f16x8 a  = __builtin_shufflevector(lo, hf, 0, 1, 2, 3, 4, 5, 6, 7);
            accB = __builtin_amdgcn_mfma_f32_32x32x16_f16(a, bfrag, accB, 0, 0, 0);
        }
    }

    // ---- store: col = lane&31 (k), row = (e&3) + 8*(e>>2) + 4*hi ----
    #pragma unroll
    for (int e = 0; e < 16; ++e) {
        int row = (e & 3) + 8 * (e >> 2) + 4 * hi;
        out[(rowbase + row) * 32 + rl]      = accA[e];
        out[(rowbase + 32 + row) * 32 + rl] = accB[e];
    }
}

extern "C" void kernel_launch(void* const* d_in, const int* in_sizes, int n_in,
                              void* d_out, int out_size, void* d_ws, size_t ws_size,
                              hipStream_t stream) {
    const float* x = (const float*)d_in[0];
    const float* W = (const float*)d_in[1];
    float* out = (float*)d_out;
    int nrows = in_sizes[0] / 32;          // 262144
    int grid  = nrows / 512;               // 512 blocks x 512 thr
    quadform_kernel<<<grid, 512, 0, stream>>>(x, W, out);
}